// Round 6
// baseline (202.095 us; speedup 1.0000x reference)
//
#include <hip/hip_runtime.h>

#define N_ATOM 10000
#define N_EDGE 40000
#define DD 64
#define BOND_DIM 10
#define EPS_BN 1e-6f
#define EPS_SM 1e-8f
#define EPB 32   // edges per block
#define EPW 8    // edges per wave
#define GA 8     // atoms per GRU block

// ---- workspace layout (float indices) ----
constexpr size_t OFF_WKP   = 0;                       // 11 planes x 4096 (k-major folded enc W, plane10 = bias)
constexpr size_t OFF_ATTWT = OFF_WKP + 11 * 4096;     // 4096  attWT[d*64+f] = folded attW[f,d]
constexpr size_t OFF_ATTB  = OFF_ATTWT + 4096;        // 64
constexpr size_t OFF_WIHT  = OFF_ATTB + 64;           // 12288 WihT[d*192+t]
constexpr size_t OFF_WHHT  = OFF_WIHT + 12288;        // 12288
constexpr size_t OFF_DENOM = OFF_WHHT + 12288;        // N_ATOM
constexpr size_t OFF_CTX   = OFF_DENOM + N_ATOM;      // N_ATOM*DD
// total 723,792 floats ~= 2.90 MB

__device__ __forceinline__ float bcast_lane(float v, int k) {
    return __uint_as_float(__builtin_amdgcn_readlane(__float_as_uint(v), k));
}

// ---------- kernel 0: fold BN into weights, build transposed layouts, zero accumulators ----------
__global__ void fold_kernel(const float* enc_W, const float* enc_b,
                            const float* g1, const float* b1,
                            const float* m1, const float* v1,
                            const float* att_W, const float* att_b,
                            const float* g2, const float* b2v,
                            const float* m2, const float* v2,
                            const float* Wih, const float* Whh,
                            float* ws) {
    int i = blockIdx.x * 256 + threadIdx.x;
    if (i < 4096) {
        float s = g1[i] * rsqrtf(v1[i] + EPS_BN);
        float t = b1[i] - m1[i] * s;
#pragma unroll
        for (int k = 0; k < BOND_DIM; k++)
            ws[OFF_WKP + (size_t)k * 4096 + i] = enc_W[i * BOND_DIM + k] * s;
        ws[OFF_WKP + (size_t)10 * 4096 + i] = enc_b[i] * s + t;
    } else if (i < 8192) {
        int j = i - 4096;
        int d = j >> 6, f = j & 63;
        float s = g2[f] * rsqrtf(v2[f] + EPS_BN);
        ws[OFF_ATTWT + j] = att_W[f * DD + d] * s;
    } else if (i < 8256) {
        int f = i - 8192;
        float s = g2[f] * rsqrtf(v2[f] + EPS_BN);
        ws[OFF_ATTB + f] = att_b[f] * s + b2v[f] - m2[f] * s;
    } else if (i < 8256 + 12288) {
        int j = i - 8256;
        int d = j / 192, t = j % 192;
        ws[OFF_WIHT + j] = Wih[t * DD + d];
    } else if (i < 8256 + 24576) {
        int j = i - 8256 - 12288;
        int d = j / 192, t = j % 192;
        ws[OFF_WHHT + j] = Whh[t * DD + d];
    } else {
        int z = i - 32832;
        if (z < N_ATOM + N_ATOM * DD) ws[OFF_DENOM + z] = 0.f;  // zero denom+ctx
    }
}

// ---------- kernel 1: fused per-edge pipeline ----------
// 256 threads = 4 waves; 8 edges/wave; thread f = lane.
// Bond coefficients are wave-uniform -> forced into SGPRs via readlane, so the
// inner chain is pure v_fma(vgpr, sgpr) with no LDS re-reads. All LDS rows are
// wave-local => no __syncthreads anywhere.
__global__ __launch_bounds__(256) void edge_kernel(
    const float* atom, const int* bidx, const float* bond,
    const float* alignW, const float* alignb,
    const float* ws, float* denom, float* ctx) {
    __shared__ float s_anbr[EPB][DD];
    __shared__ float s_nb[EPB][DD];

    const int t = threadIdx.x;
    const int lane = t & 63;
    const int wave = t >> 6;
    const int e0 = blockIdx.x * EPB;
    const int ew = e0 + wave * EPW;   // this wave's first edge

    // neighbor atom rows -> LDS (coalesced; wave-local rows)
#pragma unroll
    for (int j = 0; j < EPW; j++) {
        int nbr = bidx[2 * (ew + j) + 1];
        s_anbr[wave * EPW + j][lane] = atom[(size_t)nbr * DD + lane];
    }

    // bond coefficients -> SGPRs (lane k of one coalesced load, readlane'd)
    float bb[EPW][BOND_DIM];
#pragma unroll
    for (int j = 0; j < EPW; j++) {
        float bv = (lane < BOND_DIM) ? bond[(size_t)(ew + j) * BOND_DIM + lane] : 0.f;
#pragma unroll
        for (int k = 0; k < BOND_DIM; k++) bb[j][k] = bcast_lane(bv, k);
    }

    // main loop: neighbor[f] = sum_d anbr[d] * relu(bias + sum_k bb[k]*Wk[d*64+f])
    float acc[EPW] = {};
    const float* wkp = ws + OFF_WKP;
#pragma unroll 2
    for (int d = 0; d < DD; d++) {
        float wkv[11];
#pragma unroll
        for (int k = 0; k < 11; k++) wkv[k] = wkp[(size_t)k * 4096 + d * DD + lane];
#pragma unroll
        for (int j = 0; j < EPW; j++) {
            float v = wkv[10];
#pragma unroll
            for (int k = 0; k < BOND_DIM; k++) v = fmaf(bb[j][k], wkv[k], v);
            v = fmaxf(v, 0.f);
            acc[j] = fmaf(s_anbr[wave * EPW + j][d], v, acc[j]);
        }
    }
#pragma unroll
    for (int j = 0; j < EPW; j++) s_nb[wave * EPW + j][lane] = acc[j];

    // atend[f] = ab + sum_d attWT[d*64+f] * nb[d]   (coalesced attWT loads)
    const float ab = (ws + OFF_ATTB)[lane];
    const float* attWT = ws + OFF_ATTWT;
    float av[EPW];
#pragma unroll
    for (int j = 0; j < EPW; j++) av[j] = ab;
#pragma unroll 2
    for (int d = 0; d < DD; d++) {
        float w = attWT[d * DD + lane];
#pragma unroll
        for (int j = 0; j < EPW; j++) av[j] = fmaf(w, s_nb[wave * EPW + j][d], av[j]);
    }

    // score + exp + segment-sum atomics
    const float aw1 = alignW[lane];
    const float aw2 = alignW[64 + lane];
    const float alb = alignb[0];
#pragma unroll
    for (int j = 0; j < EPW; j++) {
        int tgt = bidx[2 * (ew + j)];          // wave-uniform scalar load
        float v = atom[(size_t)tgt * DD + lane] * aw1 + s_nb[wave * EPW + j][lane] * aw2;
#pragma unroll
        for (int off = 32; off > 0; off >>= 1) v += __shfl_xor(v, off);
        float sc = v + alb;
        sc = sc > 0.f ? sc : 0.01f * sc;       // leaky_relu slope 0.01
        float ex = expf(sc);                   // no max-shift: ratio identity, scores O(1)
        atomicAdd(&ctx[(size_t)tgt * DD + lane], ex * av[j]);
        if (lane == 0) atomicAdd(&denom[tgt], ex);
    }
}

// ---------- kernel 2: context finalize (elu) + GRU cell, transposed weights ----------
__global__ __launch_bounds__(192) void gru_kernel(
    const float* atom, const float* ws, const float* denom, const float* ctx,
    const float* bih, const float* bhh, float* out) {
    __shared__ float sctx[GA][DD];
    __shared__ float satom[GA][DD];
    __shared__ float sgi[GA][192];
    __shared__ float sgh[GA][192];
    const int a0 = blockIdx.x * GA;
    const int t = threadIdx.x;

    for (int idx = t; idx < GA * DD; idx += 192) {
        int a = idx >> 6, f = idx & 63;
        float c = ctx[(size_t)(a0 + a) * DD + f] / (denom[a0 + a] + EPS_SM);
        sctx[a][f] = c > 0.f ? c : expm1f(c);  // elu
        satom[a][f] = atom[(size_t)(a0 + a) * DD + f];
    }
    __syncthreads();

    const float* wiht = ws + OFF_WIHT;
    const float* whht = ws + OFF_WHHT;
    float gi[GA], gh[GA];
    const float bi = bih[t], bh = bhh[t];
#pragma unroll
    for (int a = 0; a < GA; a++) { gi[a] = bi; gh[a] = bh; }
#pragma unroll 4
    for (int d = 0; d < DD; d++) {
        float wi = wiht[d * 192 + t];
        float wh = whht[d * 192 + t];
#pragma unroll
        for (int a = 0; a < GA; a++) {
            gi[a] = fmaf(wi, sctx[a][d], gi[a]);
            gh[a] = fmaf(wh, satom[a][d], gh[a]);
        }
    }
#pragma unroll
    for (int a = 0; a < GA; a++) { sgi[a][t] = gi[a]; sgh[a][t] = gh[a]; }
    __syncthreads();

    for (int idx = t; idx < GA * DD; idx += 192) {
        int a = idx >> 6, f = idx & 63;
        float r = 1.f / (1.f + expf(-(sgi[a][f] + sgh[a][f])));
        float z = 1.f / (1.f + expf(-(sgi[a][64 + f] + sgh[a][64 + f])));
        float n = tanhf(sgi[a][128 + f] + r * sgh[a][128 + f]);
        out[(size_t)(a0 + a) * DD + f] = (1.f - z) * n + z * satom[a][f];
    }
}

extern "C" void kernel_launch(void* const* d_in, const int* in_sizes, int n_in,
                              void* d_out, int out_size, void* d_ws, size_t ws_size,
                              hipStream_t stream) {
    const float* atom   = (const float*)d_in[0];
    const int*   bidx   = (const int*)d_in[1];
    const float* bond   = (const float*)d_in[2];
    const float* enc_W  = (const float*)d_in[3];
    const float* enc_b  = (const float*)d_in[4];
    const float* bn1_g  = (const float*)d_in[5];
    const float* bn1_b  = (const float*)d_in[6];
    const float* bn1_m  = (const float*)d_in[7];
    const float* bn1_v  = (const float*)d_in[8];
    const float* alignW = (const float*)d_in[9];
    const float* alignb = (const float*)d_in[10];
    const float* att_W  = (const float*)d_in[11];
    const float* att_b  = (const float*)d_in[12];
    const float* bn2_g  = (const float*)d_in[13];
    const float* bn2_b  = (const float*)d_in[14];
    const float* bn2_m  = (const float*)d_in[15];
    const float* bn2_v  = (const float*)d_in[16];
    const float* gWih   = (const float*)d_in[17];
    const float* gWhh   = (const float*)d_in[18];
    const float* gbih   = (const float*)d_in[19];
    const float* gbhh   = (const float*)d_in[20];

    float* ws  = (float*)d_ws;
    float* out = (float*)d_out;

    // fold kernel also zeroes denom+ctx: 32832 param slots + 650000 zero slots
    fold_kernel<<<2668, 256, 0, stream>>>(enc_W, enc_b, bn1_g, bn1_b, bn1_m, bn1_v,
                                          att_W, att_b, bn2_g, bn2_b, bn2_m, bn2_v,
                                          gWih, gWhh, ws);

    edge_kernel<<<N_EDGE / EPB, 256, 0, stream>>>(
        atom, bidx, bond, alignW, alignb, ws,
        ws + OFF_DENOM, ws + OFF_CTX);

    gru_kernel<<<N_ATOM / GA, 192, 0, stream>>>(atom, ws, ws + OFF_DENOM, ws + OFF_CTX,
                                                gbih, gbhh, out);
}

// Round 8
// 167.823 us; speedup vs baseline: 1.2042x; 1.2042x over previous
//
#include <hip/hip_runtime.h>

#define N_ATOM 10000
#define N_EDGE 40000
#define DD 64
#define BOND_DIM 10
#define EPS_BN 1e-6f
#define EPS_SM 1e-8f
#define GA 8     // atoms per GRU block

typedef __attribute__((ext_vector_type(8))) short short8;
typedef __attribute__((ext_vector_type(4))) float float4v;
typedef unsigned int u32;

// ---- workspace layout (dword indices) ----
constexpr size_t OFF_WFRAG   = 0;        // 65536 dwords: 256 chunks x 64 lanes x 4 dwords (8 bf16 B-frag)
constexpr size_t OFF_ATTFRAG = 65536;    // 2048 dwords: 8 (fc*2+kh) x 64 lanes x 4 dwords
constexpr size_t OFF_ATTB    = 67584;    // 64
constexpr size_t OFF_WIHT    = 67648;    // 12288 WihT[d*192+t]
constexpr size_t OFF_WHHT    = 79936;    // 12288
constexpr size_t OFF_DENOM   = 92224;    // N_ATOM
constexpr size_t OFF_CTX     = 102224;   // N_ATOM*DD
// total 742,224 dwords ~= 2.97 MB

__device__ __forceinline__ unsigned short f2bf(float x) {
    u32 u = __float_as_uint(x);
    u32 r = u + 0x7FFFu + ((u >> 16) & 1u);   // RNE
    return (unsigned short)(r >> 16);
}

// ---------- kernel 0: fold BN, build MFMA B-fragments, transposes, zero accumulators ----------
__global__ void fold_kernel(const float* enc_W, const float* enc_b,
                            const float* g1, const float* b1,
                            const float* m1, const float* v1,
                            const float* att_W, const float* att_b,
                            const float* g2, const float* b2v,
                            const float* m2, const float* v2,
                            const float* Wih, const float* Whh,
                            float* ws) {
    u32* wsu = (u32*)ws;
    size_t i = (size_t)blockIdx.x * 256 + threadIdx.x;
    if (i < 16384) {
        // encoder B-fragment: chunk ch covers enc columns c = ch*16 + (l&15);
        // lane l, j=0..7 holds B[k=8*(l>>4)+j][c]; k<10 -> W'*s, k==10 -> folded bias, else 0
        int ch = i >> 6, l = i & 63, q = l >> 4;
        int c = (ch << 4) + (l & 15);
        float s = g1[c] * rsqrtf(v1[c] + EPS_BN);
        float bias = enc_b[c] * s + b1[c] - m1[c] * s;
        unsigned short h[8];
#pragma unroll
        for (int j = 0; j < 8; j++) {
            int k = 8 * q + j;
            float v = (k < BOND_DIM) ? enc_W[c * BOND_DIM + k] * s
                                     : ((k == BOND_DIM) ? bias : 0.f);
            h[j] = f2bf(v);
        }
#pragma unroll
        for (int m = 0; m < 4; m++)
            wsu[OFF_WFRAG + i * 4 + m] = (u32)h[2 * m] | ((u32)h[2 * m + 1] << 16);
    } else if (i < 16896) {
        // attention B-fragment: atend = nb(16x64) @ attWT(64x64); fckh = fc*2+kh
        int idx = i - 16384;
        int l = idx & 63, fckh = idx >> 6;
        int fc = fckh >> 1, kh = fckh & 1, q = l >> 4;
        int n = (fc << 4) + (l & 15);
        float s = g2[n] * rsqrtf(v2[n] + EPS_BN);
        unsigned short h[8];
#pragma unroll
        for (int j = 0; j < 8; j++) {
            int k = 32 * kh + 8 * q + j;
            h[j] = f2bf(att_W[n * DD + k] * s);
        }
#pragma unroll
        for (int m = 0; m < 4; m++)
            wsu[OFF_ATTFRAG + (size_t)idx * 4 + m] = (u32)h[2 * m] | ((u32)h[2 * m + 1] << 16);
    } else if (i < 16960) {
        int f = i - 16896;
        float s = g2[f] * rsqrtf(v2[f] + EPS_BN);
        ws[OFF_ATTB + f] = att_b[f] * s + b2v[f] - m2[f] * s;
    } else if (i < 29248) {
        int j = i - 16960;
        int d = j / 192, t = j % 192;
        ws[OFF_WIHT + j] = Wih[t * DD + d];
    } else if (i < 41536) {
        int j = i - 29248;
        int d = j / 192, t = j % 192;
        ws[OFF_WHHT + j] = Whh[t * DD + d];
    } else {
        size_t z = i - 41536;
        if (z < (size_t)N_ATOM + (size_t)N_ATOM * DD) ws[OFF_DENOM + z] = 0.f;
    }
}

// ---------- kernel 1: MFMA edge pipeline ----------
// 256 threads = 4 waves; 16 edges per wave (64/block). Per wave:
//   GEMM1 (MFMA): enc chunk = bond(16x32-padded) @ W'frag -> relu -> x anbr -> nb
//   GEMM2 (MFMA): atend = nb @ attWT
//   score + exp + segment atomics
__global__ __launch_bounds__(256) void edge_kernel(
    const float* atom, const int* bidx, const float* bond,
    const float* alignW, const float* alignb,
    const float* ws, float* denom, float* ctx) {
    __shared__ float s_anbr[64][65];
    __shared__ float s_nb[64][65];
    __shared__ float s_bond[64][BOND_DIM];
    __shared__ float s_ex[64];
    __shared__ int   s_tgt[64];

    const int t = threadIdx.x;
    const int lane = t & 63;
    const int wave = t >> 6;
    const int q = lane >> 4;
    const int r16 = lane & 15;
    const int we0 = wave * 16;
    const int ew = blockIdx.x * 64 + we0;   // this wave's first edge

    // stage bond rows (wave-local)
    for (int idx = lane; idx < 16 * BOND_DIM; idx += 64)
        s_bond[we0 + idx / BOND_DIM][idx % BOND_DIM] = bond[(size_t)ew * BOND_DIM + idx];
    // stage neighbor atom rows (wave-local, coalesced)
#pragma unroll 4
    for (int j = 0; j < 16; j++) {
        int nbr = bidx[2 * (ew + j) + 1];
        s_anbr[we0 + j][lane] = atom[(size_t)nbr * DD + lane];
    }

    // A fragment: A[m=r16][k=8q+j]; k<10 = bond, k==10 = 1.0 (bias), else 0
    short8 afrag;
#pragma unroll
    for (int j = 0; j < 8; j++) {
        int k = 8 * q + j;
        unsigned short h = 0;
        if (k < BOND_DIM) h = f2bf(s_bond[we0 + r16][k]);
        else if (k == BOND_DIM) h = 0x3F80u;   // 1.0
        afrag[j] = (short)h;
    }

    const short8* wfrag = (const short8*)((const u32*)ws + OFF_WFRAG);
    const float4v zero4 = {0.f, 0.f, 0.f, 0.f};
    float4v nacc[4] = {zero4, zero4, zero4, zero4};   // [fc], reg r => edge e=4q+r

#pragma unroll 2
    for (int d = 0; d < DD; d++) {
        float av0 = s_anbr[we0 + 4 * q + 0][d];
        float av1 = s_anbr[we0 + 4 * q + 1][d];
        float av2 = s_anbr[we0 + 4 * q + 2][d];
        float av3 = s_anbr[we0 + 4 * q + 3][d];
#pragma unroll
        for (int fc = 0; fc < 4; fc++) {
            short8 bfr = wfrag[(size_t)(d * 4 + fc) * 64 + lane];
            float4v e4 = __builtin_amdgcn_mfma_f32_16x16x32_bf16(afrag, bfr, zero4, 0, 0, 0);
            nacc[fc][0] = fmaf(av0, fmaxf(e4[0], 0.f), nacc[fc][0]);
            nacc[fc][1] = fmaf(av1, fmaxf(e4[1], 0.f), nacc[fc][1]);
            nacc[fc][2] = fmaf(av2, fmaxf(e4[2], 0.f), nacc[fc][2]);
            nacc[fc][3] = fmaf(av3, fmaxf(e4[3], 0.f), nacc[fc][3]);
        }
    }

    // write neighbor rows: nb[e=4q+r][f=fc*16+r16]
#pragma unroll
    for (int fc = 0; fc < 4; fc++)
#pragma unroll
        for (int r = 0; r < 4; r++)
            s_nb[we0 + 4 * q + r][fc * 16 + r16] = nacc[fc][r];

    // GEMM2: atend = nb @ attWT ; A[m=r16][k=32kh+8q+j] from s_nb (same-wave rows)
    short8 na[2];
#pragma unroll
    for (int kh = 0; kh < 2; kh++) {
#pragma unroll
        for (int j = 0; j < 8; j++)
            na[kh][j] = (short)f2bf(s_nb[we0 + r16][32 * kh + 8 * q + j]);
    }
    const short8* battfrag = (const short8*)((const u32*)ws + OFF_ATTFRAG);
    float4v att[4];
#pragma unroll
    for (int fc = 0; fc < 4; fc++) {
        att[fc] = __builtin_amdgcn_mfma_f32_16x16x32_bf16(na[0], battfrag[(fc * 2 + 0) * 64 + lane], zero4, 0, 0, 0);
        att[fc] = __builtin_amdgcn_mfma_f32_16x16x32_bf16(na[1], battfrag[(fc * 2 + 1) * 64 + lane], att[fc], 0, 0, 0);
        float ab = ws[OFF_ATTB + fc * 16 + r16];
#pragma unroll
        for (int r = 0; r < 4; r++) att[fc][r] += ab;
    }

    // score + exp (per edge, all-lane reduce), stash ex/tgt for atomic phase
    const float aw1 = alignW[lane];
    const float aw2 = alignW[64 + lane];
    const float alb = alignb[0];
#pragma unroll 4
    for (int e = 0; e < 16; e++) {
        int tgt = bidx[2 * (ew + e)];
        float v = atom[(size_t)tgt * DD + lane] * aw1 + s_nb[we0 + e][lane] * aw2;
#pragma unroll
        for (int off = 32; off > 0; off >>= 1) v += __shfl_xor(v, off);
        float sc = v + alb;
        sc = sc > 0.f ? sc : 0.01f * sc;   // leaky_relu slope 0.01
        float ex = expf(sc);               // no max-shift: ratio identity, scores O(1)
        if (lane == 0) {
            s_ex[we0 + e] = ex;
            s_tgt[we0 + e] = tgt;
            atomicAdd(&denom[tgt], ex);
        }
    }

    // segment-sum atomics for ctx (C-layout: e=4q+r, f=fc*16+r16)
#pragma unroll
    for (int r = 0; r < 4; r++) {
        float exr = s_ex[we0 + 4 * q + r];
        int tg = s_tgt[we0 + 4 * q + r];
#pragma unroll
        for (int fc = 0; fc < 4; fc++)
            atomicAdd(&ctx[(size_t)tg * DD + fc * 16 + r16], exr * att[fc][r]);
    }
}

// ---------- kernel 2: context finalize (elu) + GRU cell, transposed weights ----------
__global__ __launch_bounds__(192) void gru_kernel(
    const float* atom, const float* ws, const float* denom, const float* ctx,
    const float* bih, const float* bhh, float* out) {
    __shared__ float sctx[GA][DD];
    __shared__ float satom[GA][DD];
    __shared__ float sgi[GA][192];
    __shared__ float sgh[GA][192];
    const int a0 = blockIdx.x * GA;
    const int t = threadIdx.x;

    for (int idx = t; idx < GA * DD; idx += 192) {
        int a = idx >> 6, f = idx & 63;
        float c = ctx[(size_t)(a0 + a) * DD + f] / (denom[a0 + a] + EPS_SM);
        sctx[a][f] = c > 0.f ? c : expm1f(c);  // elu
        satom[a][f] = atom[(size_t)(a0 + a) * DD + f];
    }
    __syncthreads();

    const float* wiht = ws + OFF_WIHT;
    const float* whht = ws + OFF_WHHT;
    float gi[GA], gh[GA];
    const float bi = bih[t], bh = bhh[t];
#pragma unroll
    for (int a = 0; a < GA; a++) { gi[a] = bi; gh[a] = bh; }
#pragma unroll 4
    for (int d = 0; d < DD; d++) {
        float wi = wiht[d * 192 + t];
        float wh = whht[d * 192 + t];
#pragma unroll
        for (int a = 0; a < GA; a++) {
            gi[a] = fmaf(wi, sctx[a][d], gi[a]);
            gh[a] = fmaf(wh, satom[a][d], gh[a]);
        }
    }
#pragma unroll
    for (int a = 0; a < GA; a++) { sgi[a][t] = gi[a]; sgh[a][t] = gh[a]; }
    __syncthreads();

    for (int idx = t; idx < GA * DD; idx += 192) {
        int a = idx >> 6, f = idx & 63;
        float r = 1.f / (1.f + expf(-(sgi[a][f] + sgh[a][f])));
        float z = 1.f / (1.f + expf(-(sgi[a][64 + f] + sgh[a][64 + f])));
        float n = tanhf(sgi[a][128 + f] + r * sgh[a][128 + f]);
        out[(size_t)(a0 + a) * DD + f] = (1.f - z) * n + z * satom[a][f];
    }
}

extern "C" void kernel_launch(void* const* d_in, const int* in_sizes, int n_in,
                              void* d_out, int out_size, void* d_ws, size_t ws_size,
                              hipStream_t stream) {
    const float* atom   = (const float*)d_in[0];
    const int*   bidx   = (const int*)d_in[1];
    const float* bond   = (const float*)d_in[2];
    const float* enc_W  = (const float*)d_in[3];
    const float* enc_b  = (const float*)d_in[4];
    const float* bn1_g  = (const float*)d_in[5];
    const float* bn1_b  = (const float*)d_in[6];
    const float* bn1_m  = (const float*)d_in[7];
    const float* bn1_v  = (const float*)d_in[8];
    const float* alignW = (const float*)d_in[9];
    const float* alignb = (const float*)d_in[10];
    const float* att_W  = (const float*)d_in[11];
    const float* att_b  = (const float*)d_in[12];
    const float* bn2_g  = (const float*)d_in[13];
    const float* bn2_b  = (const float*)d_in[14];
    const float* bn2_m  = (const float*)d_in[15];
    const float* bn2_v  = (const float*)d_in[16];
    const float* gWih   = (const float*)d_in[17];
    const float* gWhh   = (const float*)d_in[18];
    const float* gbih   = (const float*)d_in[19];
    const float* gbhh   = (const float*)d_in[20];

    float* ws  = (float*)d_ws;
    float* out = (float*)d_out;

    fold_kernel<<<2702, 256, 0, stream>>>(enc_W, enc_b, bn1_g, bn1_b, bn1_m, bn1_v,
                                          att_W, att_b, bn2_g, bn2_b, bn2_m, bn2_v,
                                          gWih, gWhh, ws);

    edge_kernel<<<N_EDGE / 64, 256, 0, stream>>>(
        atom, bidx, bond, alignW, alignb, ws,
        ws + OFF_DENOM, ws + OFF_CTX);

    gru_kernel<<<N_ATOM / GA, 192, 0, stream>>>(atom, ws, ws + OFF_DENOM, ws + OFF_CTX,
                                                gbih, gbhh, out);
}

// Round 9
// 163.261 us; speedup vs baseline: 1.2379x; 1.0279x over previous
//
#include <hip/hip_runtime.h>

#define N_ATOM 10000
#define N_EDGE 40000
#define DD 64
#define BOND_DIM 10
#define EPS_BN 1e-6f
#define EPS_SM 1e-8f
#define GA 8     // atoms per GRU block

typedef __attribute__((ext_vector_type(8))) short short8;
typedef __attribute__((ext_vector_type(4))) float float4v;
typedef unsigned int u32;

// ---- workspace layout (dword indices) ----
constexpr size_t OFF_WFRAG   = 0;        // 65536 dwords: 256 chunks x 64 lanes x 4 dwords (8 bf16 B-frag)
constexpr size_t OFF_ATTFRAG = 65536;    // 2048 dwords: 8 (fc*2+kh) x 64 lanes x 4 dwords
constexpr size_t OFF_ATTB    = 67584;    // 64
constexpr size_t OFF_WIHT    = 67648;    // 12288 WihT[d*192+t]
constexpr size_t OFF_WHHT    = 79936;    // 12288
constexpr size_t OFF_DENOM   = 92224;    // N_ATOM
constexpr size_t OFF_CTX     = 102224;   // N_ATOM*DD
// total 742,224 dwords ~= 2.97 MB

__device__ __forceinline__ unsigned short f2bf(float x) {
    u32 u = __float_as_uint(x);
    u32 r = u + 0x7FFFu + ((u >> 16) & 1u);   // RNE
    return (unsigned short)(r >> 16);
}

// ---------- kernel 0: fold BN, build MFMA B-fragments, transposes, zero accumulators ----------
__global__ void fold_kernel(const float* enc_W, const float* enc_b,
                            const float* g1, const float* b1,
                            const float* m1, const float* v1,
                            const float* att_W, const float* att_b,
                            const float* g2, const float* b2v,
                            const float* m2, const float* v2,
                            const float* Wih, const float* Whh,
                            float* ws) {
    u32* wsu = (u32*)ws;
    size_t i = (size_t)blockIdx.x * 256 + threadIdx.x;
    if (i < 16384) {
        int ch = i >> 6, l = i & 63, q = l >> 4;
        int c = (ch << 4) + (l & 15);
        float s = g1[c] * rsqrtf(v1[c] + EPS_BN);
        float bias = enc_b[c] * s + b1[c] - m1[c] * s;
        unsigned short h[8];
#pragma unroll
        for (int j = 0; j < 8; j++) {
            int k = 8 * q + j;
            float v = (k < BOND_DIM) ? enc_W[c * BOND_DIM + k] * s
                                     : ((k == BOND_DIM) ? bias : 0.f);
            h[j] = f2bf(v);
        }
#pragma unroll
        for (int m = 0; m < 4; m++)
            wsu[OFF_WFRAG + i * 4 + m] = (u32)h[2 * m] | ((u32)h[2 * m + 1] << 16);
    } else if (i < 16896) {
        int idx = i - 16384;
        int l = idx & 63, fckh = idx >> 6;
        int fc = fckh >> 1, kh = fckh & 1, q = l >> 4;
        int n = (fc << 4) + (l & 15);
        float s = g2[n] * rsqrtf(v2[n] + EPS_BN);
        unsigned short h[8];
#pragma unroll
        for (int j = 0; j < 8; j++) {
            int k = 32 * kh + 8 * q + j;
            h[j] = f2bf(att_W[n * DD + k] * s);
        }
#pragma unroll
        for (int m = 0; m < 4; m++)
            wsu[OFF_ATTFRAG + (size_t)idx * 4 + m] = (u32)h[2 * m] | ((u32)h[2 * m + 1] << 16);
    } else if (i < 16960) {
        int f = i - 16896;
        float s = g2[f] * rsqrtf(v2[f] + EPS_BN);
        ws[OFF_ATTB + f] = att_b[f] * s + b2v[f] - m2[f] * s;
    } else if (i < 29248) {
        int j = i - 16960;
        int d = j / 192, t = j % 192;
        ws[OFF_WIHT + j] = Wih[t * DD + d];
    } else if (i < 41536) {
        int j = i - 29248;
        int d = j / 192, t = j % 192;
        ws[OFF_WHHT + j] = Whh[t * DD + d];
    } else {
        size_t z = i - 41536;
        if (z < (size_t)N_ATOM + (size_t)N_ATOM * DD) ws[OFF_DENOM + z] = 0.f;
    }
}

// ---------- kernel 1: MFMA edge pipeline, d-split across wave pairs ----------
// 256 threads = 4 waves = 2 groups x 2 d-halves; 32 edges/block, 1250 blocks.
// Each wave: 16-edge group g, d-half h. Prefetched wfrag stream; partial nb
// summed via LDS; phase B splits GEMM2 (h=0) and score (h=1) across the pair.
__global__ __launch_bounds__(256) void edge_kernel(
    const float* atom, const int* bidx, const float* bond,
    const float* alignW, const float* alignb,
    const float* ws, float* denom, float* ctx) {
    __shared__ float s_bond[32][BOND_DIM];
    __shared__ float s_anbr[32][65];
    __shared__ float s_nbp[2][32][65];
    __shared__ float s_ex[32];
    __shared__ int   s_tgt[32];

    const int t = threadIdx.x;
    const int lane = t & 63;
    const int wave = t >> 6;
    const int g = wave >> 1;     // edge group 0/1
    const int h = wave & 1;      // d-half 0/1
    const int q = lane >> 4;
    const int r16 = lane & 15;
    const int g16 = g * 16;
    const int e0 = blockIdx.x * 32;

    // ---- staging ----
    for (int idx = t; idx < 32 * BOND_DIM; idx += 256)
        s_bond[idx / BOND_DIM][idx % BOND_DIM] = bond[(size_t)e0 * BOND_DIM + idx];
    if (t < 32) s_tgt[t] = bidx[2 * (e0 + t)];
    for (int e = wave; e < 32; e += 4) {
        int nbr = bidx[2 * (e0 + e) + 1];
        s_anbr[e][lane] = atom[(size_t)nbr * DD + lane];
    }
    __syncthreads();

    // A fragment: A[m=r16][k=8q+j]; k<10 = bond, k==10 = 1.0 (bias), else 0
    short8 afrag;
#pragma unroll
    for (int j = 0; j < 8; j++) {
        int k = 8 * q + j;
        unsigned short hh = 0;
        if (k < BOND_DIM) hh = f2bf(s_bond[g16 + r16][k]);
        else if (k == BOND_DIM) hh = 0x3F80u;   // 1.0
        afrag[j] = (short)hh;
    }

    const short8* wfrag = (const short8*)((const u32*)ws + OFF_WFRAG);
    const float4v zero4 = {0.f, 0.f, 0.f, 0.f};
    float4v nacc[4] = {zero4, zero4, zero4, zero4};
    const int d0 = 32 * h;

    auto compute = [&](const short8 cur[4], int d) {
        float av0 = s_anbr[g16 + 4 * q + 0][d];
        float av1 = s_anbr[g16 + 4 * q + 1][d];
        float av2 = s_anbr[g16 + 4 * q + 2][d];
        float av3 = s_anbr[g16 + 4 * q + 3][d];
#pragma unroll
        for (int fc = 0; fc < 4; fc++) {
            float4v e4 = __builtin_amdgcn_mfma_f32_16x16x32_bf16(afrag, cur[fc], zero4, 0, 0, 0);
            nacc[fc][0] = fmaf(av0, fmaxf(e4[0], 0.f), nacc[fc][0]);
            nacc[fc][1] = fmaf(av1, fmaxf(e4[1], 0.f), nacc[fc][1]);
            nacc[fc][2] = fmaf(av2, fmaxf(e4[2], 0.f), nacc[fc][2]);
            nacc[fc][3] = fmaf(av3, fmaxf(e4[3], 0.f), nacc[fc][3]);
        }
    };

    // software-pipelined main loop over this wave's d-half
    short8 cur[4], nxt[4];
#pragma unroll
    for (int fc = 0; fc < 4; fc++) cur[fc] = wfrag[(size_t)(d0 * 4 + fc) * 64 + lane];
#pragma unroll 2
    for (int it = 0; it < 31; it++) {
        int d = d0 + it;
#pragma unroll
        for (int fc = 0; fc < 4; fc++) nxt[fc] = wfrag[(size_t)((d + 1) * 4 + fc) * 64 + lane];
        compute(cur, d);
#pragma unroll
        for (int fc = 0; fc < 4; fc++) cur[fc] = nxt[fc];
    }
    compute(cur, d0 + 31);

    // write partial nb: s_nbp[h][e=4q+r][f=fc*16+r16]
#pragma unroll
    for (int fc = 0; fc < 4; fc++)
#pragma unroll
        for (int r = 0; r < 4; r++)
            s_nbp[h][g16 + 4 * q + r][fc * 16 + r16] = nacc[fc][r];
    __syncthreads();

    float4v att[4];
    if (h == 0) {
        // GEMM2: atend = nb @ attWT ; A[m=r16][k=32kh+8q+j], nb = partial0+partial1
        short8 na[2];
#pragma unroll
        for (int kh = 0; kh < 2; kh++)
#pragma unroll
            for (int j = 0; j < 8; j++) {
                int k = 32 * kh + 8 * q + j;
                na[kh][j] = (short)f2bf(s_nbp[0][g16 + r16][k] + s_nbp[1][g16 + r16][k]);
            }
        const short8* battfrag = (const short8*)((const u32*)ws + OFF_ATTFRAG);
#pragma unroll
        for (int fc = 0; fc < 4; fc++) {
            att[fc] = __builtin_amdgcn_mfma_f32_16x16x32_bf16(na[0], battfrag[(fc * 2 + 0) * 64 + lane], zero4, 0, 0, 0);
            att[fc] = __builtin_amdgcn_mfma_f32_16x16x32_bf16(na[1], battfrag[(fc * 2 + 1) * 64 + lane], att[fc], 0, 0, 0);
            float ab = ws[OFF_ATTB + fc * 16 + r16];
#pragma unroll
            for (int r = 0; r < 4; r++) att[fc][r] += ab;
        }
    } else {
        // score + exp + denom atomics for this group's 16 edges
        const float aw1 = alignW[lane];
        const float aw2 = alignW[64 + lane];
        const float alb = alignb[0];
#pragma unroll 4
        for (int e = 0; e < 16; e++) {
            int le = g16 + e;
            int tgt = s_tgt[le];
            float nbv = s_nbp[0][le][lane] + s_nbp[1][le][lane];
            float v = atom[(size_t)tgt * DD + lane] * aw1 + nbv * aw2;
#pragma unroll
            for (int off = 32; off > 0; off >>= 1) v += __shfl_xor(v, off);
            float sc = v + alb;
            sc = sc > 0.f ? sc : 0.01f * sc;   // leaky_relu slope 0.01
            float ex = expf(sc);               // no max-shift: ratio identity, scores O(1)
            if (lane == 0) {
                s_ex[le] = ex;
                atomicAdd(&denom[tgt], ex);
            }
        }
    }
    __syncthreads();

    if (h == 0) {
        // ctx segment-sum atomics (C-layout: e=4q+r, f=fc*16+r16)
#pragma unroll
        for (int r = 0; r < 4; r++) {
            float exr = s_ex[g16 + 4 * q + r];
            int tg = s_tgt[g16 + 4 * q + r];
#pragma unroll
            for (int fc = 0; fc < 4; fc++)
                atomicAdd(&ctx[(size_t)tg * DD + fc * 16 + r16], exr * att[fc][r]);
        }
    }
}

// ---------- kernel 2: context finalize (elu) + GRU cell, transposed weights ----------
__global__ __launch_bounds__(192) void gru_kernel(
    const float* atom, const float* ws, const float* denom, const float* ctx,
    const float* bih, const float* bhh, float* out) {
    __shared__ float sctx[GA][DD];
    __shared__ float satom[GA][DD];
    __shared__ float sgi[GA][192];
    __shared__ float sgh[GA][192];
    const int a0 = blockIdx.x * GA;
    const int t = threadIdx.x;

    for (int idx = t; idx < GA * DD; idx += 192) {
        int a = idx >> 6, f = idx & 63;
        float c = ctx[(size_t)(a0 + a) * DD + f] / (denom[a0 + a] + EPS_SM);
        sctx[a][f] = c > 0.f ? c : expm1f(c);  // elu
        satom[a][f] = atom[(size_t)(a0 + a) * DD + f];
    }
    __syncthreads();

    const float* wiht = ws + OFF_WIHT;
    const float* whht = ws + OFF_WHHT;
    float gi[GA], gh[GA];
    const float bi = bih[t], bh = bhh[t];
#pragma unroll
    for (int a = 0; a < GA; a++) { gi[a] = bi; gh[a] = bh; }
#pragma unroll 4
    for (int d = 0; d < DD; d++) {
        float wi = wiht[d * 192 + t];
        float wh = whht[d * 192 + t];
#pragma unroll
        for (int a = 0; a < GA; a++) {
            gi[a] = fmaf(wi, sctx[a][d], gi[a]);
            gh[a] = fmaf(wh, satom[a][d], gh[a]);
        }
    }
#pragma unroll
    for (int a = 0; a < GA; a++) { sgi[a][t] = gi[a]; sgh[a][t] = gh[a]; }
    __syncthreads();

    for (int idx = t; idx < GA * DD; idx += 192) {
        int a = idx >> 6, f = idx & 63;
        float r = 1.f / (1.f + expf(-(sgi[a][f] + sgh[a][f])));
        float z = 1.f / (1.f + expf(-(sgi[a][64 + f] + sgh[a][64 + f])));
        float n = tanhf(sgi[a][128 + f] + r * sgh[a][128 + f]);
        out[(size_t)(a0 + a) * DD + f] = (1.f - z) * n + z * satom[a][f];
    }
}

extern "C" void kernel_launch(void* const* d_in, const int* in_sizes, int n_in,
                              void* d_out, int out_size, void* d_ws, size_t ws_size,
                              hipStream_t stream) {
    const float* atom   = (const float*)d_in[0];
    const int*   bidx   = (const int*)d_in[1];
    const float* bond   = (const float*)d_in[2];
    const float* enc_W  = (const float*)d_in[3];
    const float* enc_b  = (const float*)d_in[4];
    const float* bn1_g  = (const float*)d_in[5];
    const float* bn1_b  = (const float*)d_in[6];
    const float* bn1_m  = (const float*)d_in[7];
    const float* bn1_v  = (const float*)d_in[8];
    const float* alignW = (const float*)d_in[9];
    const float* alignb = (const float*)d_in[10];
    const float* att_W  = (const float*)d_in[11];
    const float* att_b  = (const float*)d_in[12];
    const float* bn2_g  = (const float*)d_in[13];
    const float* bn2_b  = (const float*)d_in[14];
    const float* bn2_m  = (const float*)d_in[15];
    const float* bn2_v  = (const float*)d_in[16];
    const float* gWih   = (const float*)d_in[17];
    const float* gWhh   = (const float*)d_in[18];
    const float* gbih   = (const float*)d_in[19];
    const float* gbhh   = (const float*)d_in[20];

    float* ws  = (float*)d_ws;
    float* out = (float*)d_out;

    fold_kernel<<<2702, 256, 0, stream>>>(enc_W, enc_b, bn1_g, bn1_b, bn1_m, bn1_v,
                                          att_W, att_b, bn2_g, bn2_b, bn2_m, bn2_v,
                                          gWih, gWhh, ws);

    edge_kernel<<<N_EDGE / 32, 256, 0, stream>>>(
        atom, bidx, bond, alignW, alignb, ws,
        ws + OFF_DENOM, ws + OFF_CTX);

    gru_kernel<<<N_ATOM / GA, 192, 0, stream>>>(atom, ws, ws + OFF_DENOM, ws + OFF_CTX,
                                                gbih, gbhh, out);
}